// Round 7
// baseline (156.704 us; speedup 1.0000x reference)
//
#include <hip/hip_runtime.h>
#include <math.h>

// loss = ALPHA * mean(level_w * (softplus(x) - x*t))
//      + BETA  * sum_{b,e} relu(sig(x[b,dst]) - sig(x[b,src])) / (B*N)
// (scatter target of the consistency add is irrelevant to the mean)
//
// R6: R5 structure (R=4 rows/block fp16-transposed in 32 KB LDS, 512 thr,
// 4 blocks/CU) + latency fixes: edge-index loads hoisted above phase 1 and
// software-pipelined 2-deep through phase 2, LDS gathers batched per iter.

#define ALPHA_C 1.0f
#define BETA_C  0.5f

constexpr int B = 4096;
constexpr int N = 4096;
constexpr int E = 16384;
constexpr int THREADS = 512;
constexpr int R = 4;            // rows per block
constexpr int EITER = E / 4 / THREADS;   // 8 pipelined edge batches

typedef _Float16 h4 __attribute__((ext_vector_type(4)));

__global__ __launch_bounds__(64) void init_out_kernel(float* out) {
    if (threadIdx.x == 0) out[0] = 0.0f;
}

__device__ __forceinline__ void fast_sig_sp(float x, float& p, float& sp) {
    // q = exp(-|x|) in (0,1]; both sigmoid and softplus from one exp
    float q = __expf(-fabsf(x));
    float d = 1.0f + q;
    float r = __builtin_amdgcn_rcpf(d);     // ~1 ulp approx reciprocal
    p  = (x >= 0.0f) ? r : q * r;           // sigmoid
    sp = fmaxf(x, 0.0f) + __logf(d);        // softplus = max(x,0)+log(1+q)
}

__global__ __launch_bounds__(THREADS, 8) void hier_loss_kernel(
    const float* __restrict__ outputs,
    const float* __restrict__ targets,
    const float* __restrict__ level_w,
    const int*   __restrict__ edge_src,
    const int*   __restrict__ edge_dst,
    float*       __restrict__ out)
{
    __shared__ h4 P[N];             // 32 KB: P[n] = fp16 p of rows r0..r0+3

    const int r0  = blockIdx.x * R;
    const int tid = threadIdx.x;

    const float4* out4 = (const float4*)outputs;
    const float4* tgt4 = (const float4*)targets;
    const float4* lw4  = (const float4*)level_w;
    const int4*   es4  = (const int4*)edge_src;
    const int4*   ed4  = (const int4*)edge_dst;

    // ---- edge-index batch 0 issued FIRST: hides its latency under phase 1
    int4 s_cur = es4[tid];
    int4 d_cur = ed4[tid];

    // ---- phase 1: BCE sum + fp16 transposed sigmoid into LDS ----
    float s1 = 0.0f;
#pragma unroll
    for (int j = 0; j < N / 4 / THREADS; ++j) {      // 2 iters
        const int n4 = tid + j * THREADS;            // float4-column index
        const float4 w = lw4[n4];
        const float wv[4] = {w.x, w.y, w.z, w.w};
        // batch ALL loads for this column group first (8 in flight)
        float4 xs[R], ts[R];
#pragma unroll
        for (int r = 0; r < R; ++r) {
            xs[r] = out4[(size_t)(r0 + r) * (N / 4) + n4];   // coalesced
            ts[r] = tgt4[(size_t)(r0 + r) * (N / 4) + n4];
        }
        h4 tmp[4];                  // tmp[k][r] = p(row r0+r, node 4*n4+k)
#pragma unroll
        for (int r = 0; r < R; ++r) {
            const float xv[4] = {xs[r].x, xs[r].y, xs[r].z, xs[r].w};
            const float tv[4] = {ts[r].x, ts[r].y, ts[r].z, ts[r].w};
#pragma unroll
            for (int k = 0; k < 4; ++k) {
                float p, sp;
                fast_sig_sp(xv[k], p, sp);
                s1 = fmaf(wv[k], sp - xv[k] * tv[k], s1);
                tmp[k][r] = (_Float16)p;
            }
        }
#pragma unroll
        for (int k = 0; k < 4; ++k) P[4 * n4 + k] = tmp[k]; // 2x ds_write_b128
    }
    __syncthreads();

    // ---- phase 2: pipelined edge gathers; one b64 read covers 4 rows ----
    h4 acc0 = {0, 0, 0, 0};
    h4 acc1 = {0, 0, 0, 0};
    const h4 zero = {0, 0, 0, 0};
#pragma unroll
    for (int j = 0; j < EITER; ++j) {
        // issue next batch's index loads before touching this batch
        int4 s_nxt, d_nxt;
        if (j + 1 < EITER) {
            s_nxt = es4[tid + (j + 1) * THREADS];
            d_nxt = ed4[tid + (j + 1) * THREADS];
        }
        // batch all 8 LDS gathers, then math
        h4 a0 = P[s_cur.x], c0 = P[d_cur.x];
        h4 a1 = P[s_cur.y], c1 = P[d_cur.y];
        h4 a2 = P[s_cur.z], c2 = P[d_cur.z];
        h4 a3 = P[s_cur.w], c3 = P[d_cur.w];
        acc0 += __builtin_elementwise_max(c0 - a0, zero);   // v_pk_* fp16
        acc1 += __builtin_elementwise_max(c1 - a1, zero);
        acc0 += __builtin_elementwise_max(c2 - a2, zero);
        acc1 += __builtin_elementwise_max(c3 - a3, zero);
        s_cur = s_nxt;
        d_cur = d_nxt;
    }
    float s2 = 0.0f;
#pragma unroll
    for (int l = 0; l < 4; ++l) s2 += (float)acc0[l] + (float)acc1[l];

    // ---- block reduce: wave64 shuffle, cross-wave via reused LDS ----
#pragma unroll
    for (int off = 32; off > 0; off >>= 1) {
        s1 += __shfl_down(s1, off, 64);
        s2 += __shfl_down(s2, off, 64);
    }
    __syncthreads();                     // all phase-2 reads done before reuse
    float* red = (float*)P;
    const int wave = tid >> 6;           // 8 waves
    const int lane = tid & 63;
    if (lane == 0) { red[wave] = s1; red[8 + wave] = s2; }
    __syncthreads();
    if (tid == 0) {
        float a = 0.0f, c = 0.0f;
#pragma unroll
        for (int w = 0; w < 8; ++w) { a += red[w]; c += red[8 + w]; }
        const float inv = 1.0f / ((float)B * (float)N);
        atomicAdd(out, (ALPHA_C * a + BETA_C * c) * inv);
    }
}

extern "C" void kernel_launch(void* const* d_in, const int* in_sizes, int n_in,
                              void* d_out, int out_size, void* d_ws, size_t ws_size,
                              hipStream_t stream) {
    const float* outputs = (const float*)d_in[0];
    const float* targets = (const float*)d_in[1];
    const float* level_w = (const float*)d_in[2];
    const int*   edge_src = (const int*)d_in[3];
    const int*   edge_dst = (const int*)d_in[4];
    float* out = (float*)d_out;

    init_out_kernel<<<1, 64, 0, stream>>>(out);
    hier_loss_kernel<<<B / R, THREADS, 0, stream>>>(outputs, targets, level_w,
                                                    edge_src, edge_dst, out);
}